// Round 1
// baseline (452.924 us; speedup 1.0000x reference)
//
#include <hip/hip_runtime.h>
#include <math.h>

#define MIN_NORM 1e-15f
#define MAXN     0.996f          // (1 - 4e-3)/sqrt(c), c=1
#define ATC      0.9999999f      // artanh clip = 1 - 1e-7 (rounds to 0.99999988f)
#define D 512
#define K 16

__device__ __forceinline__ float artanhc(float v) {
    v = fminf(fmaxf(v, -ATC), ATC);
    return 0.5f * logf((1.0f + v) / (1.0f - v));
}

__device__ __forceinline__ float reduce16(float v) {
    v += __shfl_xor(v, 1);
    v += __shfl_xor(v, 2);
    v += __shfl_xor(v, 4);
    v += __shfl_xor(v, 8);
    return v;
}

// ---------------- kernel 1: HypLinear -> logmap0, writes xt[N][16] ------------
__global__ __launch_bounds__(256) void hgcn_k1_linear(
    const float* __restrict__ x, const float* __restrict__ weight,
    const float* __restrict__ bias, float* __restrict__ xt, int N)
{
    __shared__ float xs[D];
    __shared__ float part[4];
    __shared__ float pm[4][16];
    __shared__ float hb_s[17];

    const int tid  = threadIdx.x;
    const int lane = tid & 63;
    const int wave = tid >> 6;
    const int k    = tid & 15;     // output component
    const int jg   = tid >> 4;     // j-group 0..15

    // cache W in registers: thread handles W[k][jg + 16*t], t=0..31
    float wreg[32];
#pragma unroll
    for (int t = 0; t < 32; ++t) wreg[t] = weight[k * D + jg + 16 * t];

    // hyp_bias = proj(expmap0(bias)) computed once by wave 0
    if (wave == 0) {
        float b = (lane < 16) ? bias[lane] : 0.0f;
        float b2 = reduce16(b * b);
        float bn = fmaxf(sqrtf(b2), MIN_NORM);
        float e  = tanhf(bn) * b / bn;
        float e2 = reduce16(e * e);
        float en = fmaxf(sqrtf(e2), MIN_NORM);
        float hb = (en > MAXN) ? e * (MAXN / en) : e;
        if (lane < 16) hb_s[lane] = hb;
        float hb2 = reduce16(hb * hb);
        if (lane == 0) hb_s[16] = hb2;
    }
    __syncthreads();
    const float hb_k = hb_s[k];
    const float y2   = hb_s[16];

    for (int row = blockIdx.x; row < N; row += gridDim.x) {
        const float* xr = x + (size_t)row * D;
        float v0 = xr[tid];
        float v1 = xr[tid + 256];
        xs[tid] = v0; xs[tid + 256] = v1;
        float p = v0 * v0 + v1 * v1;
#pragma unroll
        for (int m = 32; m >= 1; m >>= 1) p += __shfl_xor(p, m);
        if (lane == 0) part[wave] = p;
        __syncthreads();
        const float x2 = part[0] + part[1] + part[2] + part[3];

        // GEMM: acc = sum_j W[k][j]*x[j] over this thread's j slice
        float acc = 0.0f;
#pragma unroll
        for (int t = 0; t < 32; ++t) acc = fmaf(wreg[t], xs[jg + 16 * t], acc);
        acc += __shfl_xor(acc, 16);
        acc += __shfl_xor(acc, 32);
        if (lane < 16) pm[wave][lane] = acc;
        __syncthreads();
        const float mx = pm[0][k] + pm[1][k] + pm[2][k] + pm[3][k];

        // mobius_matvec tail
        float mx2 = reduce16(mx * mx);
        float xn  = fmaxf(sqrtf(x2), MIN_NORM);
        float mxn = fmaxf(sqrtf(mx2), MIN_NORM);
        float res = tanhf((mxn / xn) * artanhc(xn)) * mx / mxn;
        if (mx2 == 0.0f) res = 0.0f;
        // proj
        float rn2 = reduce16(res * res);
        float rn  = fmaxf(sqrtf(rn2), MIN_NORM);
        float mv  = (rn > MAXN) ? res * (MAXN / rn) : res;
        // mobius_add(mv, hyp_bias)
        float mv2 = reduce16(mv * mv);
        float xy  = reduce16(mv * hb_k);
        float coef = 1.0f + 2.0f * xy + y2;
        float num  = coef * mv + (1.0f - mv2) * hb_k;
        float den  = 1.0f + 2.0f * xy + mv2 * y2;
        float h    = num / fmaxf(den, MIN_NORM);
        // proj
        float hn2 = reduce16(h * h);
        float hn  = fmaxf(sqrtf(hn2), MIN_NORM);
        float hp  = (hn > MAXN) ? h * (MAXN / hn) : h;
        // logmap0
        float hp2 = reduce16(hp * hp);
        float pn  = fmaxf(sqrtf(hp2), MIN_NORM);
        float xtv = artanhc(pn) * hp / pn;

        if (wave == 0 && lane < 16) xt[(size_t)row * 16 + lane] = xtv;
        __syncthreads();
    }
}

// ---------------- index width detection ----------------
__global__ void hgcn_k_detect(const void* srcp, long long E, int* flag)
{
    const int tid = threadIdx.x;
    if (tid == 0) *flag = 0;
    __syncthreads();
    long long n = E / 2; if (n > 4096) n = 4096;
    int bad = 0;
    const unsigned long long* p = (const unsigned long long*)srcp;
    for (long long i = tid; i < n; i += 256)
        if (p[i] >= (1ULL << 32)) bad = 1;
    if (bad) atomicOr(flag, 1);
}

// ---------------- kernel 2: edge scatter-add into agg (= d_out) --------------
__global__ __launch_bounds__(256) void hgcn_k2_edges(
    const void* __restrict__ srcp, const void* __restrict__ dstp,
    const float* __restrict__ ew, const float* __restrict__ xt,
    float* __restrict__ agg, long long E, const int* __restrict__ flag)
{
    long long gid = (long long)blockIdx.x * blockDim.x + threadIdx.x;
    long long e = gid >> 4;
    int k = (int)(gid & 15);
    if (e >= E) return;
    long long s, d;
    if (*flag) {
        s = ((const int*)srcp)[e];
        d = ((const int*)dstp)[e];
    } else {
        s = ((const long long*)srcp)[e];
        d = ((const long long*)dstp)[e];
    }
    float w = ew[e];
    atomicAdd(&agg[d * 16 + k], w * xt[s * 16 + k]);
}

// ---------------- kernel 3: finalize in place on d_out -----------------------
__global__ __launch_bounds__(256) void hgcn_k3_final(float* __restrict__ out, int N)
{
    int gid = blockIdx.x * blockDim.x + threadIdx.x;
    int row = gid >> 4;
    int k   = gid & 15;
    if (row >= N) return;
    float u = out[(size_t)row * 16 + k];

    // h1 = proj(expmap0(u))
    float un2 = reduce16(u * u);
    float un  = fmaxf(sqrtf(un2), MIN_NORM);
    float h1  = tanhf(un) * u / un;
    float n2  = reduce16(h1 * h1);
    float n1  = fmaxf(sqrtf(n2), MIN_NORM);
    float h1p = (n1 > MAXN) ? h1 * (MAXN / n1) : h1;
    // xt2 = logmap0(h1p)
    float m2  = reduce16(h1p * h1p);
    float pn  = fmaxf(sqrtf(m2), MIN_NORM);
    float xt2 = artanhc(pn) * h1p / pn;
    // h2 = proj(expmap0(xt2))
    float a2  = reduce16(xt2 * xt2);
    float an  = fmaxf(sqrtf(a2), MIN_NORM);
    float h2  = tanhf(an) * xt2 / an;
    float b2  = reduce16(h2 * h2);
    float bn  = fmaxf(sqrtf(b2), MIN_NORM);
    float h2p = (bn > MAXN) ? h2 * (MAXN / bn) : h2;
    // out = logmap0(h2p)
    float c2  = reduce16(h2p * h2p);
    float cn  = fmaxf(sqrtf(c2), MIN_NORM);
    out[(size_t)row * 16 + k] = artanhc(cn) * h2p / cn;
}

extern "C" void kernel_launch(void* const* d_in, const int* in_sizes, int n_in,
                              void* d_out, int out_size, void* d_ws, size_t ws_size,
                              hipStream_t stream)
{
    const float* x        = (const float*)d_in[0];
    const float* weight   = (const float*)d_in[1];
    const float* bias     = (const float*)d_in[2];
    const float* edge_w   = (const float*)d_in[3];
    const void*  edge_src = d_in[4];
    const void*  edge_dst = d_in[5];

    const int Kv = in_sizes[2];          // 16
    const int Dv = in_sizes[1] / Kv;     // 512
    const int N  = in_sizes[0] / Dv;     // 100000
    const long long E = in_sizes[3];     // 3200000

    int*   flag = (int*)d_ws;
    float* xt   = (float*)((char*)d_ws + 256);
    float* agg  = (float*)d_out;

    hipMemsetAsync(d_out, 0, (size_t)N * 16 * sizeof(float), stream);
    hipLaunchKernelGGL(hgcn_k_detect, dim3(1), dim3(256), 0, stream, edge_src, E, flag);
    hipLaunchKernelGGL(hgcn_k1_linear, dim3(2048), dim3(256), 0, stream,
                       x, weight, bias, xt, N);
    long long thr = E * 16;
    hipLaunchKernelGGL(hgcn_k2_edges, dim3((unsigned)((thr + 255) / 256)), dim3(256), 0, stream,
                       edge_src, edge_dst, edge_w, xt, agg, E, flag);
    hipLaunchKernelGGL(hgcn_k3_final, dim3((unsigned)(((long long)N * 16 + 255) / 256)), dim3(256), 0, stream,
                       agg, N);
}